// Round 1
// baseline (85.581 us; speedup 1.0000x reference)
//
#include <hip/hip_runtime.h>
#include <hip/hip_bf16.h>

// BSpline1D: out = basis(x) @ coeffs + w*x + b
// Uniform knots: knots[i] = -1.75 + 0.25*i, i = 0..14 (exact in fp32).
// For x in [0,1): interval index i = 7 + j, j = floor(4x) in {0..3};
// local param u = 4x - j; nonzero cubic bases are coeffs[4+j .. 7+j] with
// standard uniform cubic blending weights.

__device__ __forceinline__ float bspline_eval(float x, const float* __restrict__ c,
                                              float w, float b) {
    float t = 4.0f * x;              // exact (power-of-2 scale)
    float fj = floorf(t);
    int j = (int)fj;
    j = min(max(j, 0), 3);           // safety clamp; x in [0,1) => j in {0..3}
    float u = t - (float)j;
    float um = 1.0f - u;
    float u2 = u * u;
    float u3 = u2 * u;
    const float k6 = 1.0f / 6.0f;
    float b0 = um * um * um * k6;
    float b1 = (3.0f * u3 - 6.0f * u2 + 4.0f) * k6;
    float b2 = (-3.0f * u3 + 3.0f * u2 + 3.0f * u + 1.0f) * k6;
    float b3 = u3 * k6;
    const float* cc = c + 4 + j;
    float s = cc[0] * b0 + cc[1] * b1 + cc[2] * b2 + cc[3] * b3;
    return fmaf(w, x, s + b);
}

__global__ __launch_bounds__(256) void bspline1d_kernel(
        const float4* __restrict__ x4,
        const float* __restrict__ coeffs,   // 11 elements
        const float* __restrict__ lw,       // 1 element
        const float* __restrict__ bias,     // 1 element
        float4* __restrict__ out4,
        int n4) {
    // Uniform (wave-invariant) parameters -> scalar loads
    float c[11];
#pragma unroll
    for (int i = 0; i < 11; ++i) c[i] = coeffs[i];
    float w = lw[0];
    float b = bias[0];

    int idx = blockIdx.x * blockDim.x + threadIdx.x;
    int stride = gridDim.x * blockDim.x;
    for (; idx < n4; idx += stride) {
        float4 v = x4[idx];
        float4 o;
        o.x = bspline_eval(v.x, c, w, b);
        o.y = bspline_eval(v.y, c, w, b);
        o.z = bspline_eval(v.z, c, w, b);
        o.w = bspline_eval(v.w, c, w, b);
        out4[idx] = o;
    }
}

__global__ void bspline1d_tail(
        const float* __restrict__ x,
        const float* __restrict__ coeffs,
        const float* __restrict__ lw,
        const float* __restrict__ bias,
        float* __restrict__ out,
        int start, int n) {
    float c[11];
#pragma unroll
    for (int i = 0; i < 11; ++i) c[i] = coeffs[i];
    float w = lw[0];
    float b = bias[0];
    int i = start + blockIdx.x * blockDim.x + threadIdx.x;
    if (i < n) out[i] = bspline_eval(x[i], c, w, b);
}

extern "C" void kernel_launch(void* const* d_in, const int* in_sizes, int n_in,
                              void* d_out, int out_size, void* d_ws, size_t ws_size,
                              hipStream_t stream) {
    const float* x      = (const float*)d_in[0];
    const float* coeffs = (const float*)d_in[1];
    const float* lw     = (const float*)d_in[2];
    const float* bias   = (const float*)d_in[3];
    float* out = (float*)d_out;
    int n  = in_sizes[0];
    int n4 = n / 4;

    if (n4 > 0) {
        int blocks = (n4 + 255) / 256;
        if (blocks > 2048) blocks = 2048;
        bspline1d_kernel<<<blocks, 256, 0, stream>>>(
            (const float4*)x, coeffs, lw, bias, (float4*)out, n4);
    }
    int tail = n - n4 * 4;
    if (tail > 0) {
        bspline1d_tail<<<1, 64, 0, stream>>>(x, coeffs, lw, bias, out, n4 * 4, n);
    }
}

// Round 3
// 79.636 us; speedup vs baseline: 1.0746x; 1.0746x over previous
//
#include <hip/hip_runtime.h>
#include <hip/hip_bf16.h>

// BSpline1D: out = basis(x) @ coeffs + w*x + b
// Uniform knots: knots[i] = -1.75 + 0.25*i (exact in fp32).
// For x in [0,1): j = floor(4x) in {0..3}, u = 4x - j; the 4 nonzero cubic
// bases are the standard uniform B-spline blend of u against coeffs[4+j..7+j].

typedef float fvec4 __attribute__((ext_vector_type(4)));  // native vec for NT builtins

__device__ __forceinline__ float bspline_eval(float x, const float* __restrict__ c,
                                              float w, float b) {
    float t = 4.0f * x;              // exact (power-of-2 scale)
    float fj = floorf(t);
    int j = (int)fj;
    j = min(max(j, 0), 3);           // x in [0,1) => j in {0..3}
    float u = t - (float)j;
    float um = 1.0f - u;
    float u2 = u * u;
    float u3 = u2 * u;
    const float k6 = 1.0f / 6.0f;
    float b0 = um * um * um * k6;
    float b1 = fmaf(3.0f, u3, fmaf(-6.0f, u2, 4.0f)) * k6;
    float b2 = fmaf(-3.0f, u3, fmaf(3.0f, u2, fmaf(3.0f, u, 1.0f))) * k6;
    float b3 = u3 * k6;
    const float* cc = c + 4 + j;
    float s = fmaf(cc[0], b0, fmaf(cc[1], b1, fmaf(cc[2], b2, cc[3] * b3)));
    return fmaf(w, x, s + b);
}

__global__ __launch_bounds__(256) void bspline1d_kernel(
        const fvec4* __restrict__ x4,
        const float* __restrict__ coeffs,   // 11 elements
        const float* __restrict__ lw,       // 1 element
        const float* __restrict__ bias,     // 1 element
        fvec4* __restrict__ out4,
        int n4) {
    int idx = blockIdx.x * 256 + threadIdx.x;
    if (idx >= n4) return;

    // Wave-uniform parameters -> scalar (s_load) reads, cached
    float c[11];
#pragma unroll
    for (int i = 0; i < 11; ++i) c[i] = coeffs[i];
    float w = lw[0];
    float b = bias[0];

    fvec4 v = x4[idx];               // cache-warm (restored just before launch)
    fvec4 o;
    o.x = bspline_eval(v.x, c, w, b);
    o.y = bspline_eval(v.y, c, w, b);
    o.z = bspline_eval(v.z, c, w, b);
    o.w = bspline_eval(v.w, c, w, b);
    __builtin_nontemporal_store(o, &out4[idx]);   // out is never re-read by us
}

__global__ void bspline1d_tail(
        const float* __restrict__ x,
        const float* __restrict__ coeffs,
        const float* __restrict__ lw,
        const float* __restrict__ bias,
        float* __restrict__ out,
        int start, int n) {
    float c[11];
#pragma unroll
    for (int i = 0; i < 11; ++i) c[i] = coeffs[i];
    float w = lw[0];
    float b = bias[0];
    int i = start + blockIdx.x * blockDim.x + threadIdx.x;
    if (i < n) out[i] = bspline_eval(x[i], c, w, b);
}

extern "C" void kernel_launch(void* const* d_in, const int* in_sizes, int n_in,
                              void* d_out, int out_size, void* d_ws, size_t ws_size,
                              hipStream_t stream) {
    const float* x      = (const float*)d_in[0];
    const float* coeffs = (const float*)d_in[1];
    const float* lw     = (const float*)d_in[2];
    const float* bias   = (const float*)d_in[3];
    float* out = (float*)d_out;
    int n  = in_sizes[0];
    int n4 = n / 4;

    if (n4 > 0) {
        int blocks = (n4 + 255) / 256;     // exact grid, one float4 per thread
        bspline1d_kernel<<<blocks, 256, 0, stream>>>(
            (const fvec4*)x, coeffs, lw, bias, (fvec4*)out, n4);
    }
    int tail = n - n4 * 4;
    if (tail > 0) {
        bspline1d_tail<<<1, 64, 0, stream>>>(x, coeffs, lw, bias, out, n4 * 4, n);
    }
}